// Round 1
// baseline (1165.897 us; speedup 1.0000x reference)
//
#include <hip/hip_runtime.h>
#include <hip/hip_bf16.h>
#include <math.h>

#define D 128
#define DPAD 136   // +8 bf16 pad: row stride 272B = 68 words -> rows shift 4 banks
#define BM 64      // edge/node rows per block

typedef __attribute__((ext_vector_type(8))) short bf16x8;
typedef __attribute__((ext_vector_type(4))) float f32x4;

__device__ __forceinline__ unsigned short f2bf(float f) {
    unsigned int u = __float_as_uint(f);
    unsigned int r = u + 0x7fffu + ((u >> 16) & 1u);
    return (unsigned short)(r >> 16);
}

__device__ __forceinline__ float silu(float x) {
    return x / (1.f + __expf(-x));
}

// ---------------- weight convert: 4 x [128x128] f32 -> bf16 -------------
__global__ void convert_weights(const float* __restrict__ a, const float* __restrict__ b,
                                const float* __restrict__ c, const float* __restrict__ d,
                                unsigned short* __restrict__ o) {
    int i = blockIdx.x * 256 + threadIdx.x;          // 0..65535
    const float* p = (i < 16384) ? a : (i < 32768) ? b : (i < 49152) ? c : d;
    o[i] = f2bf(p[i & 16383]);
}

// ---------------- edge-degree counts (int) ------------------------------
__global__ void count_edges(const int* __restrict__ tgt_idx, int* __restrict__ cnt, int n_edge) {
    int i = blockIdx.x * 256 + threadIdx.x;
    if (i < n_edge) atomicAdd(&cnt[tgt_idx[i]], 1);
}

// ---------------- counting-sort scaffolding -----------------------------
// exclusive prefix sum over cnt[n_tgt] -> cursor[], then scatter edge ids.

__global__ void scan_chunks(const int* __restrict__ cnt, int* __restrict__ chunk_sum, int n) {
    int i = blockIdx.x * 256 + threadIdx.x;
    int v = (i < n) ? cnt[i] : 0;
#pragma unroll
    for (int m = 1; m < 64; m <<= 1) v += __shfl_xor(v, m);
    __shared__ int ws[4];
    if ((threadIdx.x & 63) == 0) ws[threadIdx.x >> 6] = v;
    __syncthreads();
    if (threadIdx.x == 0) chunk_sum[blockIdx.x] = ws[0] + ws[1] + ws[2] + ws[3];
}

// single block; nc <= 256 (n_tgt <= 65536)
__global__ void scan_offsets(int* __restrict__ chunk_sum, int nc) {
    int tid = threadIdx.x;
    int v = (tid < nc) ? chunk_sum[tid] : 0;
    int lane = tid & 63, w = tid >> 6;
    int s = v;
#pragma unroll
    for (int m = 1; m < 64; m <<= 1) { int t = __shfl_up(s, m); if (lane >= m) s += t; }
    __shared__ int wsum[4];
    if (lane == 63) wsum[w] = s;
    __syncthreads();
    int base = 0;
    for (int k = 0; k < w; ++k) base += wsum[k];
    if (tid < nc) chunk_sum[tid] = base + s - v;     // exclusive
}

__global__ void scan_final(const int* __restrict__ cnt, const int* __restrict__ chunk_off,
                           int* __restrict__ cursor, int n) {
    int tid = threadIdx.x, i = blockIdx.x * 256 + tid;
    int v = (i < n) ? cnt[i] : 0;
    int lane = tid & 63, w = tid >> 6;
    int s = v;
#pragma unroll
    for (int m = 1; m < 64; m <<= 1) { int t = __shfl_up(s, m); if (lane >= m) s += t; }
    __shared__ int wsum[4];
    if (lane == 63) wsum[w] = s;
    __syncthreads();
    int base = chunk_off[blockIdx.x];
    for (int k = 0; k < w; ++k) base += wsum[k];
    if (i < n) cursor[i] = base + s - v;             // exclusive start, doubles as cursor
}

__global__ void fill_edges(const int* __restrict__ tgt_idx, int* __restrict__ cursor,
                           int* __restrict__ edge_ids, int n_edge) {
    int i = blockIdx.x * 256 + threadIdx.x;
    if (i < n_edge) {
        int p = atomicAdd(&cursor[tgt_idx[i]], 1);
        edge_ids[p] = i;
    }
}

// ---------------- shared GEMM core pieces -------------------------------
// Block: 256 thr = 4 waves; tile BM x 128 out, K = 128.
// Wave w computes rows [w*16, w*16+16). Per wave: 8 col-tiles x 4 k-steps MFMA.

__device__ __forceinline__ void stage_B(const unsigned short* __restrict__ Wb,
                                        unsigned short (*Bs)[DPAD], int tid) {
    const int4* src = (const int4*)Wb;               // 8 shorts per chunk; 16 chunks/row
#pragma unroll
    for (int i = 0; i < 8; ++i) {                    // 2048 chunks = 128 rows x 16 chunks
        int linear = tid + i * 256;
        int row = linear >> 4, c8 = (linear & 15) * 8;
        *(int4*)&Bs[row][c8] = src[linear];
    }
}

// ---------------- projection GEMM: O = A @ W^T (fp32 in, fp32 out) ------
__global__ __launch_bounds__(256) void proj_kernel(const float* __restrict__ A,
                                                   const unsigned short* __restrict__ Wb,
                                                   float* __restrict__ O, int M) {
    __shared__ unsigned short As[BM][DPAD];
    __shared__ unsigned short Bs[D][DPAD];
    int tid = threadIdx.x;
    int m0 = blockIdx.x * BM;
    stage_B(Wb, Bs, tid);
#pragma unroll
    for (int i = 0; i < 8; ++i) {                    // 2048 float4 chunks
        int linear = tid + i * 256;
        int row = linear >> 5, c4 = (linear & 31) * 4;
        int gr = m0 + row; if (gr >= M) gr = M - 1;
        float4 v = *(const float4*)&A[(size_t)gr * D + c4];
        unsigned int lo = (unsigned int)f2bf(v.x) | ((unsigned int)f2bf(v.y) << 16);
        unsigned int hi = (unsigned int)f2bf(v.z) | ((unsigned int)f2bf(v.w) << 16);
        *(uint2*)&As[row][c4] = make_uint2(lo, hi);
    }
    __syncthreads();

    int wid = tid >> 6, lane = tid & 63, q = lane >> 4, ln = lane & 15;
    f32x4 acc[8];
#pragma unroll
    for (int nt = 0; nt < 8; ++nt) acc[nt] = (f32x4){0.f, 0.f, 0.f, 0.f};
    int arow = wid * 16 + ln;
#pragma unroll
    for (int k0 = 0; k0 < 128; k0 += 32) {
        bf16x8 a = *(const bf16x8*)&As[arow][k0 + q * 8];
#pragma unroll
        for (int nt = 0; nt < 8; ++nt) {
            bf16x8 b = *(const bf16x8*)&Bs[nt * 16 + ln][k0 + q * 8];
            acc[nt] = __builtin_amdgcn_mfma_f32_16x16x32_bf16(a, b, acc[nt], 0, 0, 0);
        }
    }
#pragma unroll
    for (int r = 0; r < 4; ++r) {
        int grow = m0 + wid * 16 + q * 4 + r;
        if (grow < M) {
#pragma unroll
            for (int nt = 0; nt < 8; ++nt)
                O[(size_t)grow * D + nt * 16 + ln] = acc[nt][r];
        }
    }
}

// ---------------- fused edge kernel (tgt-sorted order) ------------------
// Processes edges in counting-sorted order (edge_ids permutation) so each
// block sees runs of equal tgt. Computes add_feat, writes edge_out[e] in
// original indexing, then does an in-LDS segmented reduction over runs and
// issues ONE atomic row per run into sums[t] (~13x fewer atomics, no HBM
// RMW thrash of the 20.5MB sums array).
__global__ __launch_bounds__(256) void edge_kernel(const float* __restrict__ edge_feat,
                                                   const unsigned short* __restrict__ We2e_b,
                                                   const float* __restrict__ Sp,
                                                   const float* __restrict__ Tp,
                                                   const int* __restrict__ src_idx,
                                                   const int* __restrict__ tgt_idx,
                                                   const int* __restrict__ edge_ids,
                                                   const float* __restrict__ gamma1,
                                                   const float* __restrict__ beta1,
                                                   float* __restrict__ edge_out,
                                                   float* __restrict__ sums,
                                                   int n_edge) {
    // Fs overlays As+Bs: both are dead after the MFMA loop (barrier-guarded).
    __shared__ union {
        struct { unsigned short As[BM][DPAD]; unsigned short Bs[D][DPAD]; } ab;
        float Fs[BM][D];
    } sm;
    __shared__ int eid_s[BM];
    __shared__ int trow_s[BM];

    int tid = threadIdx.x;
    int e0 = blockIdx.x * BM;

    if (tid < BM) {
        int ge = e0 + tid;
        eid_s[tid] = edge_ids[ge < n_edge ? ge : n_edge - 1];
    }
    stage_B(We2e_b, sm.ab.Bs, tid);
    __syncthreads();                                  // eid_s ready for A staging

#pragma unroll
    for (int i = 0; i < 8; ++i) {
        int linear = tid + i * 256;
        int row = linear >> 5, c4 = (linear & 31) * 4;
        int e = eid_s[row];
        float4 v = *(const float4*)&edge_feat[(size_t)e * D + c4];
        unsigned int lo = (unsigned int)f2bf(v.x) | ((unsigned int)f2bf(v.y) << 16);
        unsigned int hi = (unsigned int)f2bf(v.z) | ((unsigned int)f2bf(v.w) << 16);
        *(uint2*)&sm.ab.As[row][c4] = make_uint2(lo, hi);
    }
    __syncthreads();

    int wid = tid >> 6, lane = tid & 63, q = lane >> 4, ln = lane & 15;
    f32x4 acc[8];
#pragma unroll
    for (int nt = 0; nt < 8; ++nt) acc[nt] = (f32x4){0.f, 0.f, 0.f, 0.f};
    int arow = wid * 16 + ln;
#pragma unroll
    for (int k0 = 0; k0 < 128; k0 += 32) {
        bf16x8 a = *(const bf16x8*)&sm.ab.As[arow][k0 + q * 8];
#pragma unroll
        for (int nt = 0; nt < 8; ++nt) {
            bf16x8 b = *(const bf16x8*)&sm.ab.Bs[nt * 16 + ln][k0 + q * 8];
            acc[nt] = __builtin_amdgcn_mfma_f32_16x16x32_bf16(a, b, acc[nt], 0, 0, 0);
        }
    }

    float g[8], bt[8];
#pragma unroll
    for (int nt = 0; nt < 8; ++nt) { g[nt] = gamma1[nt * 16 + ln]; bt[nt] = beta1[nt * 16 + ln]; }

    __syncthreads();                                  // As/Bs dead -> Fs overlay safe

#pragma unroll
    for (int r = 0; r < 4; ++r) {
        int row = wid * 16 + q * 4 + r;               // uniform across the 16-lane quad
        bool valid = (e0 + row) < n_edge;
        int e = eid_s[row];
        int s = src_idx[e], t = tgt_idx[e];
        if (ln == 0) trow_s[row] = valid ? t : -1;
        float h[8], sum = 0.f, sumsq = 0.f;
#pragma unroll
        for (int nt = 0; nt < 8; ++nt) {
            int c = nt * 16 + ln;
            float v = acc[nt][r] + Sp[(size_t)s * D + c] + Tp[(size_t)t * D + c];
            v = silu(v);
            h[nt] = v; sum += v; sumsq += v * v;
        }
#pragma unroll
        for (int m = 1; m < 16; m <<= 1) {            // row lives on 16 lanes of this quad
            sum += __shfl_xor(sum, m);
            sumsq += __shfl_xor(sumsq, m);
        }
        float mean = sum * (1.f / 128.f);
        float var = sumsq * (1.f / 128.f) - mean * mean;
        float rs = rsqrtf(var + 1e-5f);
#pragma unroll
        for (int nt = 0; nt < 8; ++nt) {
            int c = nt * 16 + ln;
            float a = (h[nt] - mean) * rs * g[nt] + bt[nt];
            sm.Fs[row][c] = a;                        // stage for segmented reduce
            if (valid)
                edge_out[(size_t)e * D + c] = edge_feat[(size_t)e * D + c] + a;
        }
    }
    __syncthreads();

    // segmented reduction: one atomic row per run of equal t.
    {
        int row = tid >> 2, part = tid & 3;           // 4 threads per row, 32 cols each
        int t = trow_s[row];
        bool head = (t >= 0) && (row == 0 || trow_s[row - 1] != t);
        if (head) {
            int L = 1;
            while (row + L < BM && trow_s[row + L] == t) ++L;
            f32x4 a4[8];
#pragma unroll
            for (int k = 0; k < 8; ++k) a4[k] = (f32x4){0.f, 0.f, 0.f, 0.f};
            for (int j = 0; j < L; ++j) {
                const float* fp = &sm.Fs[row + j][part * 32];
#pragma unroll
                for (int k = 0; k < 8; ++k) {
                    f32x4 v = *(const f32x4*)&fp[k * 4];
                    a4[k] += v;
                }
            }
            float* sp = &sums[(size_t)t * D + part * 32];
#pragma unroll
            for (int k = 0; k < 8; ++k) {
#pragma unroll
                for (int j = 0; j < 4; ++j)
                    unsafeAtomicAdd(&sp[k * 4 + j], a4[k][j]);
            }
        }
    }
}

// ---------------- fused node kernel -------------------------------------
// agg = sums/max(cnt,1); acc = agg @ We2t^T; h = acc + Ttp; silu; LN;
// tgt_out = tgt_feat + a
__global__ __launch_bounds__(256) void node_kernel(const float* __restrict__ sums,
                                                   const int* __restrict__ cnt,
                                                   const unsigned short* __restrict__ We2t_b,
                                                   const float* __restrict__ Ttp,
                                                   const float* __restrict__ tgt_feat,
                                                   const float* __restrict__ gamma2,
                                                   const float* __restrict__ beta2,
                                                   float* __restrict__ tgt_out,
                                                   int n_tgt) {
    __shared__ unsigned short As[BM][DPAD];
    __shared__ unsigned short Bs[D][DPAD];
    int tid = threadIdx.x;
    int m0 = blockIdx.x * BM;
    stage_B(We2t_b, Bs, tid);
#pragma unroll
    for (int i = 0; i < 8; ++i) {
        int linear = tid + i * 256;
        int row = linear >> 5, c4 = (linear & 31) * 4;
        int gr = m0 + row; if (gr >= n_tgt) gr = n_tgt - 1;
        float rcp = 1.f / fmaxf((float)cnt[gr], 1.f);
        float4 v = *(const float4*)&sums[(size_t)gr * D + c4];
        unsigned int lo = (unsigned int)f2bf(v.x * rcp) | ((unsigned int)f2bf(v.y * rcp) << 16);
        unsigned int hi = (unsigned int)f2bf(v.z * rcp) | ((unsigned int)f2bf(v.w * rcp) << 16);
        *(uint2*)&As[row][c4] = make_uint2(lo, hi);
    }
    __syncthreads();

    int wid = tid >> 6, lane = tid & 63, q = lane >> 4, ln = lane & 15;
    f32x4 acc[8];
#pragma unroll
    for (int nt = 0; nt < 8; ++nt) acc[nt] = (f32x4){0.f, 0.f, 0.f, 0.f};
    int arow = wid * 16 + ln;
#pragma unroll
    for (int k0 = 0; k0 < 128; k0 += 32) {
        bf16x8 a = *(const bf16x8*)&As[arow][k0 + q * 8];
#pragma unroll
        for (int nt = 0; nt < 8; ++nt) {
            bf16x8 b = *(const bf16x8*)&Bs[nt * 16 + ln][k0 + q * 8];
            acc[nt] = __builtin_amdgcn_mfma_f32_16x16x32_bf16(a, b, acc[nt], 0, 0, 0);
        }
    }

    float g[8], bt[8];
#pragma unroll
    for (int nt = 0; nt < 8; ++nt) { g[nt] = gamma2[nt * 16 + ln]; bt[nt] = beta2[nt * 16 + ln]; }

#pragma unroll
    for (int r = 0; r < 4; ++r) {
        int row = m0 + wid * 16 + q * 4 + r;
        if (row >= n_tgt) continue;
        float h[8], sum = 0.f, sumsq = 0.f;
#pragma unroll
        for (int nt = 0; nt < 8; ++nt) {
            int c = nt * 16 + ln;
            float v = acc[nt][r] + Ttp[(size_t)row * D + c];
            v = silu(v);
            h[nt] = v; sum += v; sumsq += v * v;
        }
#pragma unroll
        for (int m = 1; m < 16; m <<= 1) {
            sum += __shfl_xor(sum, m);
            sumsq += __shfl_xor(sumsq, m);
        }
        float mean = sum * (1.f / 128.f);
        float var = sumsq * (1.f / 128.f) - mean * mean;
        float rs = rsqrtf(var + 1e-5f);
#pragma unroll
        for (int nt = 0; nt < 8; ++nt) {
            int c = nt * 16 + ln;
            float a = (h[nt] - mean) * rs * g[nt] + bt[nt];
            tgt_out[(size_t)row * D + c] = tgt_feat[(size_t)row * D + c] + a;
        }
    }
}

extern "C" void kernel_launch(void* const* d_in, const int* in_sizes, int n_in,
                              void* d_out, int out_size, void* d_ws, size_t ws_size,
                              hipStream_t stream) {
    const float* src_feat  = (const float*)d_in[0];
    const float* tgt_feat  = (const float*)d_in[1];
    const float* edge_feat = (const float*)d_in[2];
    const float* Ws2e = (const float*)d_in[3];
    const float* We2e = (const float*)d_in[4];
    const float* We2t = (const float*)d_in[5];
    const float* Wt2t = (const float*)d_in[6];
    const float* gamma1 = (const float*)d_in[7];
    const float* beta1  = (const float*)d_in[8];
    const float* gamma2 = (const float*)d_in[9];
    const float* beta2  = (const float*)d_in[10];
    const int* src_idx = (const int*)d_in[11];
    const int* tgt_idx = (const int*)d_in[12];

    int n_src  = in_sizes[0] / D;
    int n_tgt  = in_sizes[1] / D;
    int n_edge = in_sizes[2] / D;

    float* edge_out = (float*)d_out;
    float* tgt_out  = (float*)d_out + (size_t)n_edge * D;

    // workspace layout
    char* ws = (char*)d_ws;
    unsigned short* Wb = (unsigned short*)ws;                     // 4 * 16384 bf16 = 128 KB
    float* Sp     = (float*)(ws + 4 * 16384 * 2);                 // [n_src, D]
    float* Tp     = Sp + (size_t)n_src * D;                       // [n_tgt, D]
    float* Ttp    = Tp + (size_t)n_tgt * D;                       // [n_tgt, D]
    float* sums   = Ttp + (size_t)n_tgt * D;                      // [n_tgt, D]
    int*   cnt    = (int*)(sums + (size_t)n_tgt * D);             // [n_tgt]
    int*   cursor = cnt + n_tgt;                                  // [n_tgt]
    int*   chunk  = cursor + n_tgt;                               // [nc]
    int nc = (n_tgt + 255) / 256;
    int*   edge_ids = chunk + ((nc + 63) & ~63);                  // [n_edge]

    // zero sums + cnt (contiguous)
    hipMemsetAsync(sums, 0, ((size_t)n_tgt * D + n_tgt) * sizeof(float), stream);

    convert_weights<<<256, 256, 0, stream>>>(Ws2e, We2e, We2t, Wt2t, Wb);
    count_edges<<<(n_edge + 255) / 256, 256, 0, stream>>>(tgt_idx, cnt, n_edge);
    scan_chunks<<<nc, 256, 0, stream>>>(cnt, chunk, n_tgt);
    scan_offsets<<<1, 256, 0, stream>>>(chunk, nc);
    scan_final<<<nc, 256, 0, stream>>>(cnt, chunk, cursor, n_tgt);
    fill_edges<<<(n_edge + 255) / 256, 256, 0, stream>>>(tgt_idx, cursor, edge_ids, n_edge);

    // node projections through Ws2e (and tgt through Wt2t)
    proj_kernel<<<(n_src + BM - 1) / BM, 256, 0, stream>>>(src_feat, Wb,             Sp,  n_src);
    proj_kernel<<<(n_tgt + BM - 1) / BM, 256, 0, stream>>>(tgt_feat, Wb,             Tp,  n_tgt);
    proj_kernel<<<(n_tgt + BM - 1) / BM, 256, 0, stream>>>(tgt_feat, Wb + 3 * 16384, Ttp, n_tgt);

    edge_kernel<<<(n_edge + BM - 1) / BM, 256, 0, stream>>>(
        edge_feat, Wb + 16384, Sp, Tp, src_idx, tgt_idx, edge_ids, gamma1, beta1,
        edge_out, sums, n_edge);

    node_kernel<<<(n_tgt + BM - 1) / BM, 256, 0, stream>>>(
        sums, cnt, Wb + 2 * 16384, Ttp, tgt_feat, gamma2, beta2,
        tgt_out, n_tgt);
}

// Round 2
// 989.086 us; speedup vs baseline: 1.1788x; 1.1788x over previous
//
#include <hip/hip_runtime.h>
#include <hip/hip_bf16.h>
#include <math.h>

#define D 128
#define DPAD 136   // +8 bf16 pad: row stride 272B = 68 words -> rows shift 4 banks
#define BM 64      // edge/node rows per block

typedef __attribute__((ext_vector_type(8))) short bf16x8;
typedef __attribute__((ext_vector_type(4))) float f32x4;

__device__ __forceinline__ unsigned short f2bf(float f) {
    unsigned int u = __float_as_uint(f);
    unsigned int r = u + 0x7fffu + ((u >> 16) & 1u);
    return (unsigned short)(r >> 16);
}

__device__ __forceinline__ float bf2f(unsigned short u) {
    return __uint_as_float((unsigned int)u << 16);
}

__device__ __forceinline__ float silu(float x) {
    return x / (1.f + __expf(-x));
}

// ---------------- weight convert: 4 x [128x128] f32 -> bf16 -------------
__global__ void convert_weights(const float* __restrict__ a, const float* __restrict__ b,
                                const float* __restrict__ c, const float* __restrict__ d,
                                unsigned short* __restrict__ o) {
    int i = blockIdx.x * 256 + threadIdx.x;          // 0..65535
    const float* p = (i < 16384) ? a : (i < 32768) ? b : (i < 49152) ? c : d;
    o[i] = f2bf(p[i & 16383]);
}

// ---------------- edge-degree counts (int) ------------------------------
__global__ void count_edges(const int* __restrict__ tgt_idx, int* __restrict__ cnt, int n_edge) {
    int i = blockIdx.x * 256 + threadIdx.x;
    if (i < n_edge) atomicAdd(&cnt[tgt_idx[i]], 1);
}

// ---------------- counting-sort scaffolding -----------------------------
__global__ void scan_chunks(const int* __restrict__ cnt, int* __restrict__ chunk_sum, int n) {
    int i = blockIdx.x * 256 + threadIdx.x;
    int v = (i < n) ? cnt[i] : 0;
#pragma unroll
    for (int m = 1; m < 64; m <<= 1) v += __shfl_xor(v, m);
    __shared__ int ws[4];
    if ((threadIdx.x & 63) == 0) ws[threadIdx.x >> 6] = v;
    __syncthreads();
    if (threadIdx.x == 0) chunk_sum[blockIdx.x] = ws[0] + ws[1] + ws[2] + ws[3];
}

// single block; nc <= 256 (n_tgt <= 65536)
__global__ void scan_offsets(int* __restrict__ chunk_sum, int nc) {
    int tid = threadIdx.x;
    int v = (tid < nc) ? chunk_sum[tid] : 0;
    int lane = tid & 63, w = tid >> 6;
    int s = v;
#pragma unroll
    for (int m = 1; m < 64; m <<= 1) { int t = __shfl_up(s, m); if (lane >= m) s += t; }
    __shared__ int wsum[4];
    if (lane == 63) wsum[w] = s;
    __syncthreads();
    int base = 0;
    for (int k = 0; k < w; ++k) base += wsum[k];
    if (tid < nc) chunk_sum[tid] = base + s - v;     // exclusive
}

__global__ void scan_final(const int* __restrict__ cnt, const int* __restrict__ chunk_off,
                           int* __restrict__ starts, int* __restrict__ cursor, int n) {
    int tid = threadIdx.x, i = blockIdx.x * 256 + tid;
    int v = (i < n) ? cnt[i] : 0;
    int lane = tid & 63, w = tid >> 6;
    int s = v;
#pragma unroll
    for (int m = 1; m < 64; m <<= 1) { int t = __shfl_up(s, m); if (lane >= m) s += t; }
    __shared__ int wsum[4];
    if (lane == 63) wsum[w] = s;
    __syncthreads();
    int base = chunk_off[blockIdx.x];
    for (int k = 0; k < w; ++k) base += wsum[k];
    if (i < n) {
        int ex = base + s - v;                       // exclusive start
        starts[i] = ex;
        cursor[i] = ex;
    }
}

// pos[e] = slot of edge e in tgt-sorted layout (streaming; atomics hit a
// 160KB L2-resident cursor array only)
__global__ void fill_pos(const int* __restrict__ tgt_idx, int* __restrict__ cursor,
                         int* __restrict__ pos, int n_edge) {
    int i = blockIdx.x * 256 + threadIdx.x;
    if (i < n_edge) pos[i] = atomicAdd(&cursor[tgt_idx[i]], 1);
}

// ---------------- shared GEMM core pieces -------------------------------
__device__ __forceinline__ void stage_B(const unsigned short* __restrict__ Wb,
                                        unsigned short (*Bs)[DPAD], int tid) {
    const int4* src = (const int4*)Wb;               // 8 shorts per chunk; 16 chunks/row
#pragma unroll
    for (int i = 0; i < 8; ++i) {                    // 2048 chunks = 128 rows x 16 chunks
        int linear = tid + i * 256;
        int row = linear >> 4, c8 = (linear & 15) * 8;
        *(int4*)&Bs[row][c8] = src[linear];
    }
}

// ---------------- projection GEMM: O = A @ W^T (fp32 in, fp32 out) ------
__global__ __launch_bounds__(256) void proj_kernel(const float* __restrict__ A,
                                                   const unsigned short* __restrict__ Wb,
                                                   float* __restrict__ O, int M) {
    __shared__ unsigned short As[BM][DPAD];
    __shared__ unsigned short Bs[D][DPAD];
    int tid = threadIdx.x;
    int m0 = blockIdx.x * BM;
    stage_B(Wb, Bs, tid);
#pragma unroll
    for (int i = 0; i < 8; ++i) {                    // 2048 float4 chunks
        int linear = tid + i * 256;
        int row = linear >> 5, c4 = (linear & 31) * 4;
        int gr = m0 + row; if (gr >= M) gr = M - 1;
        float4 v = *(const float4*)&A[(size_t)gr * D + c4];
        unsigned int lo = (unsigned int)f2bf(v.x) | ((unsigned int)f2bf(v.y) << 16);
        unsigned int hi = (unsigned int)f2bf(v.z) | ((unsigned int)f2bf(v.w) << 16);
        *(uint2*)&As[row][c4] = make_uint2(lo, hi);
    }
    __syncthreads();

    int wid = tid >> 6, lane = tid & 63, q = lane >> 4, ln = lane & 15;
    f32x4 acc[8];
#pragma unroll
    for (int nt = 0; nt < 8; ++nt) acc[nt] = (f32x4){0.f, 0.f, 0.f, 0.f};
    int arow = wid * 16 + ln;
#pragma unroll
    for (int k0 = 0; k0 < 128; k0 += 32) {
        bf16x8 a = *(const bf16x8*)&As[arow][k0 + q * 8];
#pragma unroll
        for (int nt = 0; nt < 8; ++nt) {
            bf16x8 b = *(const bf16x8*)&Bs[nt * 16 + ln][k0 + q * 8];
            acc[nt] = __builtin_amdgcn_mfma_f32_16x16x32_bf16(a, b, acc[nt], 0, 0, 0);
        }
    }
#pragma unroll
    for (int r = 0; r < 4; ++r) {
        int grow = m0 + wid * 16 + q * 4 + r;
        if (grow < M) {
#pragma unroll
            for (int nt = 0; nt < 8; ++nt)
                O[(size_t)grow * D + nt * 16 + ln] = acc[nt][r];
        }
    }
}

// ---------------- fused edge kernel (streaming, scatter a_srt) ----------
// Edges processed in ORIGINAL order: edge_feat read + edge_out write stay
// fully streamed. Instead of 82M f32 atomics, the LN output `a` is packed
// to bf16 in the (dead) As tile and written as ONE contiguous 256B row per
// edge into tgt-sorted slot pos[e]. Zero atomics, zero RMW.
__global__ __launch_bounds__(256) void edge_kernel_scatter(
        const float* __restrict__ edge_feat,
        const unsigned short* __restrict__ We2e_b,
        const float* __restrict__ Sp,
        const float* __restrict__ Tp,
        const int* __restrict__ src_idx,
        const int* __restrict__ tgt_idx,
        const int* __restrict__ pos,
        const float* __restrict__ gamma1,
        const float* __restrict__ beta1,
        float* __restrict__ edge_out,
        unsigned short* __restrict__ a_srt,
        int n_edge) {
    __shared__ unsigned short As[BM][DPAD];
    __shared__ unsigned short Bs[D][DPAD];
    __shared__ int pos_s[BM];
    int tid = threadIdx.x;
    int e0 = blockIdx.x * BM;
    stage_B(We2e_b, Bs, tid);
#pragma unroll
    for (int i = 0; i < 8; ++i) {
        int linear = tid + i * 256;
        int row = linear >> 5, c4 = (linear & 31) * 4;
        int gr = e0 + row; if (gr >= n_edge) gr = n_edge - 1;
        float4 v = *(const float4*)&edge_feat[(size_t)gr * D + c4];
        unsigned int lo = (unsigned int)f2bf(v.x) | ((unsigned int)f2bf(v.y) << 16);
        unsigned int hi = (unsigned int)f2bf(v.z) | ((unsigned int)f2bf(v.w) << 16);
        *(uint2*)&As[row][c4] = make_uint2(lo, hi);
    }
    __syncthreads();

    int wid = tid >> 6, lane = tid & 63, q = lane >> 4, ln = lane & 15;
    f32x4 acc[8];
#pragma unroll
    for (int nt = 0; nt < 8; ++nt) acc[nt] = (f32x4){0.f, 0.f, 0.f, 0.f};
    int arow = wid * 16 + ln;
#pragma unroll
    for (int k0 = 0; k0 < 128; k0 += 32) {
        bf16x8 a = *(const bf16x8*)&As[arow][k0 + q * 8];
#pragma unroll
        for (int nt = 0; nt < 8; ++nt) {
            bf16x8 b = *(const bf16x8*)&Bs[nt * 16 + ln][k0 + q * 8];
            acc[nt] = __builtin_amdgcn_mfma_f32_16x16x32_bf16(a, b, acc[nt], 0, 0, 0);
        }
    }

    float g[8], bt[8];
#pragma unroll
    for (int nt = 0; nt < 8; ++nt) { g[nt] = gamma1[nt * 16 + ln]; bt[nt] = beta1[nt * 16 + ln]; }

    __syncthreads();                                  // all MFMA done -> As reusable

#pragma unroll
    for (int r = 0; r < 4; ++r) {
        int row = wid * 16 + q * 4 + r;               // uniform across the 16-lane quad
        int e = e0 + row;
        bool valid = e < n_edge;
        int ec = valid ? e : n_edge - 1;
        int s = src_idx[ec], t = tgt_idx[ec];
        if (ln == 0) pos_s[row] = valid ? pos[ec] : -1;
        float h[8], sum = 0.f, sumsq = 0.f;
#pragma unroll
        for (int nt = 0; nt < 8; ++nt) {
            int c = nt * 16 + ln;
            float v = acc[nt][r] + Sp[(size_t)s * D + c] + Tp[(size_t)t * D + c];
            v = silu(v);
            h[nt] = v; sum += v; sumsq += v * v;
        }
#pragma unroll
        for (int m = 1; m < 16; m <<= 1) {            // row lives on 16 lanes of this quad
            sum += __shfl_xor(sum, m);
            sumsq += __shfl_xor(sumsq, m);
        }
        float mean = sum * (1.f / 128.f);
        float var = sumsq * (1.f / 128.f) - mean * mean;
        float rs = rsqrtf(var + 1e-5f);
#pragma unroll
        for (int nt = 0; nt < 8; ++nt) {
            int c = nt * 16 + ln;
            float a = (h[nt] - mean) * rs * g[nt] + bt[nt];
            if (valid)
                edge_out[(size_t)e * D + c] = edge_feat[(size_t)e * D + c] + a;
            As[row][c] = f2bf(a);                     // pack for row-scatter
        }
    }
    __syncthreads();

    // write each edge's bf16 row (256B contiguous) to its sorted slot
    {
        int row = tid >> 2, seg = tid & 3;            // 4 threads/row, 64B each
        int p = pos_s[row];
        if (p >= 0) {
            const int4* s4 = (const int4*)&As[row][seg * 32];
            int4* d4 = (int4*)&a_srt[(size_t)p * D + seg * 32];
            d4[0] = s4[0]; d4[1] = s4[1]; d4[2] = s4[2]; d4[3] = s4[3];
        }
    }
}

// ---------------- fallback edge kernel (round-0 atomics) ----------------
__global__ __launch_bounds__(256) void edge_kernel_atomic(
        const float* __restrict__ edge_feat,
        const unsigned short* __restrict__ We2e_b,
        const float* __restrict__ Sp,
        const float* __restrict__ Tp,
        const int* __restrict__ src_idx,
        const int* __restrict__ tgt_idx,
        const float* __restrict__ gamma1,
        const float* __restrict__ beta1,
        float* __restrict__ edge_out,
        float* __restrict__ sums,
        int n_edge) {
    __shared__ unsigned short As[BM][DPAD];
    __shared__ unsigned short Bs[D][DPAD];
    int tid = threadIdx.x;
    int e0 = blockIdx.x * BM;
    stage_B(We2e_b, Bs, tid);
#pragma unroll
    for (int i = 0; i < 8; ++i) {
        int linear = tid + i * 256;
        int row = linear >> 5, c4 = (linear & 31) * 4;
        int gr = e0 + row; if (gr >= n_edge) gr = n_edge - 1;
        float4 v = *(const float4*)&edge_feat[(size_t)gr * D + c4];
        unsigned int lo = (unsigned int)f2bf(v.x) | ((unsigned int)f2bf(v.y) << 16);
        unsigned int hi = (unsigned int)f2bf(v.z) | ((unsigned int)f2bf(v.w) << 16);
        *(uint2*)&As[row][c4] = make_uint2(lo, hi);
    }
    __syncthreads();

    int wid = tid >> 6, lane = tid & 63, q = lane >> 4, ln = lane & 15;
    f32x4 acc[8];
#pragma unroll
    for (int nt = 0; nt < 8; ++nt) acc[nt] = (f32x4){0.f, 0.f, 0.f, 0.f};
    int arow = wid * 16 + ln;
#pragma unroll
    for (int k0 = 0; k0 < 128; k0 += 32) {
        bf16x8 a = *(const bf16x8*)&As[arow][k0 + q * 8];
#pragma unroll
        for (int nt = 0; nt < 8; ++nt) {
            bf16x8 b = *(const bf16x8*)&Bs[nt * 16 + ln][k0 + q * 8];
            acc[nt] = __builtin_amdgcn_mfma_f32_16x16x32_bf16(a, b, acc[nt], 0, 0, 0);
        }
    }

    float g[8], bt[8];
#pragma unroll
    for (int nt = 0; nt < 8; ++nt) { g[nt] = gamma1[nt * 16 + ln]; bt[nt] = beta1[nt * 16 + ln]; }

#pragma unroll
    for (int r = 0; r < 4; ++r) {
        int e = e0 + wid * 16 + q * 4 + r;
        if (e >= n_edge) continue;
        int s = src_idx[e], t = tgt_idx[e];
        float h[8], sum = 0.f, sumsq = 0.f;
#pragma unroll
        for (int nt = 0; nt < 8; ++nt) {
            int c = nt * 16 + ln;
            float v = acc[nt][r] + Sp[(size_t)s * D + c] + Tp[(size_t)t * D + c];
            v = silu(v);
            h[nt] = v; sum += v; sumsq += v * v;
        }
#pragma unroll
        for (int m = 1; m < 16; m <<= 1) {
            sum += __shfl_xor(sum, m);
            sumsq += __shfl_xor(sumsq, m);
        }
        float mean = sum * (1.f / 128.f);
        float var = sumsq * (1.f / 128.f) - mean * mean;
        float rs = rsqrtf(var + 1e-5f);
#pragma unroll
        for (int nt = 0; nt < 8; ++nt) {
            int c = nt * 16 + ln;
            float a = (h[nt] - mean) * rs * g[nt] + bt[nt];
            edge_out[(size_t)e * D + c] = edge_feat[(size_t)e * D + c] + a;
            atomicAdd(&sums[(size_t)t * D + c], a);
        }
    }
}

// ---------------- fused node kernel -------------------------------------
// mode 1: agg[t] = mean over contiguous run a_srt[starts[t] .. +cnt[t]]
// mode 0: agg[t] = sums[t]/max(cnt,1)  (fallback)
__global__ __launch_bounds__(256) void node_kernel(const float* __restrict__ sums,
                                                   const unsigned short* __restrict__ a_srt,
                                                   const int* __restrict__ starts,
                                                   const int* __restrict__ cnt,
                                                   const unsigned short* __restrict__ We2t_b,
                                                   const float* __restrict__ Ttp,
                                                   const float* __restrict__ tgt_feat,
                                                   const float* __restrict__ gamma2,
                                                   const float* __restrict__ beta2,
                                                   float* __restrict__ tgt_out,
                                                   int n_tgt, int mode) {
    __shared__ unsigned short As[BM][DPAD];
    __shared__ unsigned short Bs[D][DPAD];
    int tid = threadIdx.x;
    int m0 = blockIdx.x * BM;
    stage_B(We2t_b, Bs, tid);
#pragma unroll
    for (int i = 0; i < 8; ++i) {
        int linear = tid + i * 256;
        int row = linear >> 5, c4 = (linear & 31) * 4;
        int gr = m0 + row; if (gr >= n_tgt) gr = n_tgt - 1;
        int n = cnt[gr];
        float rcp = 1.f / fmaxf((float)n, 1.f);
        float s0, s1, s2, s3;
        if (mode) {
            int st = starts[gr];
            s0 = s1 = s2 = s3 = 0.f;
            for (int j = 0; j < n; ++j) {
                uint2 u = *(const uint2*)&a_srt[((size_t)(st + j)) * D + c4];
                s0 += bf2f((unsigned short)(u.x & 0xffffu));
                s1 += bf2f((unsigned short)(u.x >> 16));
                s2 += bf2f((unsigned short)(u.y & 0xffffu));
                s3 += bf2f((unsigned short)(u.y >> 16));
            }
        } else {
            float4 v = *(const float4*)&sums[(size_t)gr * D + c4];
            s0 = v.x; s1 = v.y; s2 = v.z; s3 = v.w;
        }
        unsigned int lo = (unsigned int)f2bf(s0 * rcp) | ((unsigned int)f2bf(s1 * rcp) << 16);
        unsigned int hi = (unsigned int)f2bf(s2 * rcp) | ((unsigned int)f2bf(s3 * rcp) << 16);
        *(uint2*)&As[row][c4] = make_uint2(lo, hi);
    }
    __syncthreads();

    int wid = tid >> 6, lane = tid & 63, q = lane >> 4, ln = lane & 15;
    f32x4 acc[8];
#pragma unroll
    for (int nt = 0; nt < 8; ++nt) acc[nt] = (f32x4){0.f, 0.f, 0.f, 0.f};
    int arow = wid * 16 + ln;
#pragma unroll
    for (int k0 = 0; k0 < 128; k0 += 32) {
        bf16x8 a = *(const bf16x8*)&As[arow][k0 + q * 8];
#pragma unroll
        for (int nt = 0; nt < 8; ++nt) {
            bf16x8 b = *(const bf16x8*)&Bs[nt * 16 + ln][k0 + q * 8];
            acc[nt] = __builtin_amdgcn_mfma_f32_16x16x32_bf16(a, b, acc[nt], 0, 0, 0);
        }
    }

    float g[8], bt[8];
#pragma unroll
    for (int nt = 0; nt < 8; ++nt) { g[nt] = gamma2[nt * 16 + ln]; bt[nt] = beta2[nt * 16 + ln]; }

#pragma unroll
    for (int r = 0; r < 4; ++r) {
        int row = m0 + wid * 16 + q * 4 + r;
        if (row >= n_tgt) continue;
        float h[8], sum = 0.f, sumsq = 0.f;
#pragma unroll
        for (int nt = 0; nt < 8; ++nt) {
            int c = nt * 16 + ln;
            float v = acc[nt][r] + Ttp[(size_t)row * D + c];
            v = silu(v);
            h[nt] = v; sum += v; sumsq += v * v;
        }
#pragma unroll
        for (int m = 1; m < 16; m <<= 1) {
            sum += __shfl_xor(sum, m);
            sumsq += __shfl_xor(sumsq, m);
        }
        float mean = sum * (1.f / 128.f);
        float var = sumsq * (1.f / 128.f) - mean * mean;
        float rs = rsqrtf(var + 1e-5f);
#pragma unroll
        for (int nt = 0; nt < 8; ++nt) {
            int c = nt * 16 + ln;
            float a = (h[nt] - mean) * rs * g[nt] + bt[nt];
            tgt_out[(size_t)row * D + c] = tgt_feat[(size_t)row * D + c] + a;
        }
    }
}

extern "C" void kernel_launch(void* const* d_in, const int* in_sizes, int n_in,
                              void* d_out, int out_size, void* d_ws, size_t ws_size,
                              hipStream_t stream) {
    const float* src_feat  = (const float*)d_in[0];
    const float* tgt_feat  = (const float*)d_in[1];
    const float* edge_feat = (const float*)d_in[2];
    const float* Ws2e = (const float*)d_in[3];
    const float* We2e = (const float*)d_in[4];
    const float* We2t = (const float*)d_in[5];
    const float* Wt2t = (const float*)d_in[6];
    const float* gamma1 = (const float*)d_in[7];
    const float* beta1  = (const float*)d_in[8];
    const float* gamma2 = (const float*)d_in[9];
    const float* beta2  = (const float*)d_in[10];
    const int* src_idx = (const int*)d_in[11];
    const int* tgt_idx = (const int*)d_in[12];

    int n_src  = in_sizes[0] / D;
    int n_tgt  = in_sizes[1] / D;
    int n_edge = in_sizes[2] / D;

    float* edge_out = (float*)d_out;
    float* tgt_out  = (float*)d_out + (size_t)n_edge * D;

    // workspace layout
    char* ws = (char*)d_ws;
    size_t off = 0;
    unsigned short* Wb = (unsigned short*)(ws + off); off += (size_t)4 * 16384 * 2;
    float* Sp     = (float*)(ws + off); off += (size_t)n_src * D * 4;
    float* Tp     = (float*)(ws + off); off += (size_t)n_tgt * D * 4;
    float* Ttp    = (float*)(ws + off); off += (size_t)n_tgt * D * 4;
    float* sums   = (float*)(ws + off); off += (size_t)n_tgt * D * 4;   // fallback only
    int*   cnt    = (int*)(ws + off);   off += (size_t)n_tgt * 4;
    int*   cursor = (int*)(ws + off);   off += (size_t)n_tgt * 4;
    int*   starts = (int*)(ws + off);   off += (size_t)n_tgt * 4;
    int*   chunk  = (int*)(ws + off);   off += 256 * 4;
    int*   pos    = (int*)(ws + off);   off += (size_t)n_edge * 4;
    off = (off + 255) & ~(size_t)255;
    unsigned short* a_srt = (unsigned short*)(ws + off);
    size_t needed = off + (size_t)n_edge * D * 2;
    int use_scatter = (ws_size >= needed) ? 1 : 0;

    int nc = (n_tgt + 255) / 256;

    if (use_scatter) {
        hipMemsetAsync(cnt, 0, (size_t)n_tgt * 4, stream);
        count_edges<<<(n_edge + 255) / 256, 256, 0, stream>>>(tgt_idx, cnt, n_edge);
        scan_chunks<<<nc, 256, 0, stream>>>(cnt, chunk, n_tgt);
        scan_offsets<<<1, 256, 0, stream>>>(chunk, nc);
        scan_final<<<nc, 256, 0, stream>>>(cnt, chunk, starts, cursor, n_tgt);
        fill_pos<<<(n_edge + 255) / 256, 256, 0, stream>>>(tgt_idx, cursor, pos, n_edge);
    } else {
        hipMemsetAsync(sums, 0, (size_t)n_tgt * D * 4, stream);
        hipMemsetAsync(cnt, 0, (size_t)n_tgt * 4, stream);
        count_edges<<<(n_edge + 255) / 256, 256, 0, stream>>>(tgt_idx, cnt, n_edge);
    }

    convert_weights<<<256, 256, 0, stream>>>(Ws2e, We2e, We2t, Wt2t, Wb);

    // node projections through Ws2e (and tgt through Wt2t)
    proj_kernel<<<(n_src + BM - 1) / BM, 256, 0, stream>>>(src_feat, Wb,             Sp,  n_src);
    proj_kernel<<<(n_tgt + BM - 1) / BM, 256, 0, stream>>>(tgt_feat, Wb,             Tp,  n_tgt);
    proj_kernel<<<(n_tgt + BM - 1) / BM, 256, 0, stream>>>(tgt_feat, Wb + 3 * 16384, Ttp, n_tgt);

    if (use_scatter) {
        edge_kernel_scatter<<<(n_edge + BM - 1) / BM, 256, 0, stream>>>(
            edge_feat, Wb + 16384, Sp, Tp, src_idx, tgt_idx, pos, gamma1, beta1,
            edge_out, a_srt, n_edge);
    } else {
        edge_kernel_atomic<<<(n_edge + BM - 1) / BM, 256, 0, stream>>>(
            edge_feat, Wb + 16384, Sp, Tp, src_idx, tgt_idx, gamma1, beta1,
            edge_out, sums, n_edge);
    }

    node_kernel<<<(n_tgt + BM - 1) / BM, 256, 0, stream>>>(
        sums, a_srt, starts, cnt, Wb + 2 * 16384, Ttp, tgt_feat, gamma2, beta2,
        tgt_out, n_tgt, use_scatter);
}